// Round 10
// baseline (669.809 us; speedup 1.0000x reference)
//
#include <hip/hip_runtime.h>
#include <hip/hip_fp16.h>

#define HID 128   // feature width (D == H == 128)

// ---------------- bf16 helpers ----------------
__device__ __forceinline__ float bf2f(unsigned short u) {
    union { unsigned int i; float f; } v;
    v.i = ((unsigned int)u) << 16;
    return v.f;
}
__device__ __forceinline__ unsigned short f2bf(float f) {
    union { float f; unsigned int i; } v;
    v.f = f;
    unsigned int lsb = (v.i >> 16) & 1u;
    v.i += 0x7fffu + lsb;   // round-to-nearest-even
    return (unsigned short)(v.i >> 16);
}

// ---------------- fp8 e4m3fn helpers ----------------
// t = h@W is stored fp8 (128B/row = one cache line).
template <int S>
__device__ __forceinline__ float fp8_dec(unsigned int v) {
#if __has_builtin(__builtin_amdgcn_cvt_f32_fp8)
    return __builtin_amdgcn_cvt_f32_fp8(v, S);
#else
    unsigned int b = (v >> (S * 8)) & 0xffu;
    unsigned short u = (unsigned short)(((b & 0x80u) << 8) | ((b & 0x7fu) << 7));
    return __half2float(__ushort_as_half(u)) * 256.0f;
#endif
}
// encode: clamp to +-448, f32->f16 (hw RNE), then RNE 10->3 mantissa bits.
__device__ __forceinline__ unsigned char fp8_enc(float f) {
    f = fminf(fmaxf(f, -448.f), 448.f);
    unsigned short u = __half_as_ushort(__float2half(f * 0.00390625f)); // /256
    unsigned short r = (unsigned short)(u + (((u >> 7) & 1u) + 0x3fu));
    return (unsigned char)(((r >> 7) & 0x7fu) | ((u >> 8) & 0x80u));
}

typedef __attribute__((ext_vector_type(8))) short bf16x8;   // 8 bf16 (4 VGPRs)
typedef __attribute__((ext_vector_type(4))) float f32x4;    // MFMA acc

// ---------------- MFMA GEMM body (C = A @ W, fp8 out) ------------------------
__device__ __forceinline__ bf16x8 a_frag_load(const unsigned short* p) {
    return *(const bf16x8*)p;
}
__device__ __forceinline__ bf16x8 a_frag_load(const float* p) {
    bf16x8 r;
#pragma unroll
    for (int i = 0; i < 8; ++i) r[i] = (short)f2bf(p[i]);
    return r;
}

template <typename TA>
__device__ __forceinline__ void gemm_body(const TA* __restrict__ A,
                                          const unsigned short* __restrict__ B,
                                          unsigned char* __restrict__ C,
                                          int N, int blk) {
    const int tid = threadIdx.x;
    const int lane = tid & 63, wave = tid >> 6;
    const int q = lane >> 4, c = lane & 15;
    const int rowBase = blk * 128 + wave * 32;

    f32x4 acc[2][8];
#pragma unroll
    for (int rt = 0; rt < 2; ++rt)
#pragma unroll
        for (int ct = 0; ct < 8; ++ct)
            acc[rt][ct] = (f32x4){0.f, 0.f, 0.f, 0.f};

    const bf16x8 zfrag = {};
#pragma unroll
    for (int ks = 0; ks < 4; ++ks) {
        bf16x8 a[2];
#pragma unroll
        for (int rt = 0; rt < 2; ++rt) {
            int r = rowBase + rt * 16 + c;
            a[rt] = (r < N) ? a_frag_load(A + (size_t)r * HID + ks * 32 + q * 8)
                            : zfrag;
        }
#pragma unroll
        for (int ct = 0; ct < 8; ++ct) {
            bf16x8 b = *(const bf16x8*)&B[((((ks * 8 + ct) * 4 + q) * 16 + c) << 3)];
            acc[0][ct] = __builtin_amdgcn_mfma_f32_16x16x32_bf16(a[0], b, acc[0][ct], 0, 0, 0);
            acc[1][ct] = __builtin_amdgcn_mfma_f32_16x16x32_bf16(a[1], b, acc[1][ct], 0, 0, 0);
        }
    }
#pragma unroll
    for (int rt = 0; rt < 2; ++rt)
#pragma unroll
        for (int reg = 0; reg < 4; ++reg) {
            int r = rowBase + rt * 16 + q * 4 + reg;
            if (r < N) {
#pragma unroll
                for (int ct = 0; ct < 8; ++ct)
                    C[(size_t)r * HID + ct * 16 + c] = fp8_enc(acc[rt][ct][reg]);
            }
        }
}

// ---------------- K1: histogram(+rank) || layer-0 GEMM || wprep || gbounds ---
// The 1.6M device-scope histogram atomics are latency/serialization-bound
// (r9: 73us, VALUBusy 0.5%, WRITE 56MB = atomic write-through) -- they leave
// the CUs idle. The layer-0 GEMM is data-independent of them, so its blocks
// ride in the same kernel and backfill the issue slots. GEMM blocks swizzle
// raw W1 (f32, L3-resident) into LDS themselves (can't read Wg: wprep runs
// in this same kernel). Block roles: [0,degGrid) histogram; [.. +gemmGrid)
// GEMM; [.. +256) wprep W1..W4; rest gbounds.
__global__ __launch_bounds__(256) void k_prep_gemm(
        const int* __restrict__ col, int* __restrict__ degI, int* __restrict__ rank,
        const float* __restrict__ x, const float* __restrict__ W1,
        unsigned char* __restrict__ buf0,
        const float* __restrict__ W2, const float* __restrict__ W3,
        const float* __restrict__ W4, unsigned short* __restrict__ Wg,
        const int* __restrict__ batch, int* __restrict__ gstart,
        int E, int N, int G, int degGrid, int gemmGrid) {
    __shared__ unsigned short Wsw[16384];   // 32 KB (GEMM blocks only)
    int bid = blockIdx.x;
    if (bid < degGrid) {                    // ---- degree histogram + rank ----
        int i = bid * 256 + threadIdx.x;
        if (i < E) rank[i] = atomicAdd(&degI[col[i]], 1);
        return;
    }
    bid -= degGrid;
    if (bid < gemmGrid) {                   // ---- layer-0 GEMM, self-swizzle ----
#pragma unroll 4
        for (int tt = 0; tt < 64; ++tt) {
            int i = tt * 256 + threadIdx.x;
            int k = i >> 7, n = i & 127;
            int ks = k >> 5, q = (k >> 3) & 3, j = k & 7;
            int ct = n >> 4, c = n & 15;
            Wsw[((((ks * 8 + ct) * 4 + q) * 16 + c) << 3) + j] = f2bf(W1[i]);
        }
        __syncthreads();
        gemm_body<float>(x, Wsw, buf0, N, bid);
        return;
    }
    bid -= gemmGrid;
    if (bid < 256) {                        // ---- W pre-swizzle (layers 2..5) ----
        int m = bid >> 6;                   // matrix index 0..3 (0 unused now)
        int i = (bid & 63) * 256 + threadIdx.x;
        const float* Wm = (m == 0) ? W1 : (m == 1) ? W2 : (m == 2) ? W3 : W4;
        int k = i >> 7, n = i & 127;
        int ks = k >> 5, q = (k >> 3) & 3, j = k & 7;
        int ct = n >> 4, c = n & 15;
        Wg[m * 16384 + ((((ks * 8 + ct) * 4 + q) * 16 + c) << 3) + j] = f2bf(Wm[i]);
        return;
    }
    bid -= 256;                             // ---- graph bounds ----
    int g = bid * 256 + threadIdx.x;
    if (g > G) return;
    int lo = 0, hi = N;
    while (lo < hi) {
        int mid = (lo + hi) >> 1;
        if (batch[mid] < g) lo = mid + 1; else hi = mid;
    }
    gstart[g] = lo;
}

// ---- 3-phase device-wide exclusive scan of (degI[i]+1) -> indptr ----
__global__ void k_scan_part(const int* __restrict__ degI, int* __restrict__ partial,
                            int* __restrict__ sums, int N) {
    __shared__ int sh[1024];
    int tid = threadIdx.x;
    int i = blockIdx.x * 1024 + tid;
    int v = (i < N) ? (degI[i] + 1) : 0;
    sh[tid] = v;
    __syncthreads();
    for (int off = 1; off < 1024; off <<= 1) {
        int t = (tid >= off) ? sh[tid - off] : 0;
        __syncthreads();
        sh[tid] += t;
        __syncthreads();
    }
    if (i < N) partial[i] = sh[tid] - v;
    if (tid == 1023) sums[blockIdx.x] = sh[1023];
}
__global__ void k_scan_tops(int* __restrict__ sums, int* __restrict__ indptr,
                            int nblocks, int N) {
    __shared__ int sh[1024];
    int tid = threadIdx.x;
    int v = (tid < nblocks) ? sums[tid] : 0;
    sh[tid] = v;
    __syncthreads();
    for (int off = 1; off < 1024; off <<= 1) {
        int t = (tid >= off) ? sh[tid - off] : 0;
        __syncthreads();
        sh[tid] += t;
        __syncthreads();
    }
    if (tid < nblocks) sums[tid] = sh[tid] - v;   // exclusive
    if (tid == 1023) indptr[N] = sh[1023];        // grand total = E + N
}
// phase 3: emit indptr + dinv = 1/sqrt(deg+1)
__global__ void k_scan_fix(const int* __restrict__ partial, const int* __restrict__ sums,
                           const int* __restrict__ degI, int* __restrict__ indptr,
                           float* __restrict__ dinv, int N) {
    int i = blockIdx.x * blockDim.x + threadIdx.x;
    if (i < N) {
        indptr[i] = partial[i] + sums[i >> 10];
        dinv[i] = 1.0f / sqrtf((float)(degI[i] + 1));
    }
}

// ---------------- atomic-free CSR scatter (standalone) -----------------------
// p = indptr[d] + rank[e]; self-loops take the last slot indptr[d+1]-1.
// adj entries stay 8B int2 (r9 evidence); 8B-store merge amplification is
// intrinsic (r6).
__global__ __launch_bounds__(256) void k_scat(const int* __restrict__ row,
                                              const int* __restrict__ col,
                                              const float* __restrict__ dinv,
                                              const int* __restrict__ indptr,
                                              const int* __restrict__ rank,
                                              int2* __restrict__ adj,
                                              int E, int N) {
    int e = blockIdx.x * blockDim.x + threadIdx.x;
    if (e >= E + N) return;
    int s, d, p;
    if (e < E) { s = row[e]; d = col[e]; p = indptr[d] + rank[e]; }
    else       { s = d = e - E; p = indptr[d + 1] - 1; }   // self loop: last slot
    adj[p] = make_int2(s, __float_as_int(dinv[s] * dinv[d]));
}

// ---------------- mean-pool body (one wave per graph, 8-deep unroll) ---------
__device__ __forceinline__ void pool_body(const unsigned short* __restrict__ h,
                                          const int* __restrict__ gstart,
                                          float* __restrict__ pbuf,
                                          int layer, int g, int lane) {
    int s = gstart[g], e = gstart[g + 1];
    float sx[4] = {0.f, 0.f, 0.f, 0.f};
    float sy[4] = {0.f, 0.f, 0.f, 0.f};
    int v = s;
    for (; v + 7 < e; v += 8) {
        unsigned int pk[8];
#pragma unroll
        for (int u = 0; u < 8; ++u)
            pk[u] = ((const unsigned int*)(h + (size_t)(v + u) * HID))[lane];
#pragma unroll
        for (int u = 0; u < 8; ++u) {
            sx[u & 3] += bf2f((unsigned short)(pk[u] & 0xffffu));
            sy[u & 3] += bf2f((unsigned short)(pk[u] >> 16));
        }
    }
    for (; v < e; ++v) {
        unsigned int pk = ((const unsigned int*)(h + (size_t)v * HID))[lane];
        sx[0] += bf2f((unsigned short)(pk & 0xffffu));
        sy[0] += bf2f((unsigned short)(pk >> 16));
    }
    float inv = 1.0f / fmaxf((float)(e - s), 1.0f);
    float ox = ((sx[0] + sx[1]) + (sx[2] + sx[3])) * inv;
    float oy = ((sy[0] + sy[1]) + (sy[2] + sy[3])) * inv;
    float* dst = pbuf + (size_t)g * 640 + layer * HID + lane * 2;
    dst[0] = ox;
    dst[1] = oy;
}

// layers 2..5 GEMM (bf16 h in, fp8 t out) + pool rider on h_{L-1} (same
// buffer the GEMM reads -> no race); hides 4 of the 5 pools.
__global__ __launch_bounds__(256) void k_gemm_pool(const unsigned short* __restrict__ A,
                                                   const unsigned short* __restrict__ Wg,
                                                   unsigned char* __restrict__ C,
                                                   int N,
                                                   const int* __restrict__ gstart,
                                                   float* __restrict__ pbuf,
                                                   int poolLayer, int G, int gemmGrid) {
    if (blockIdx.x < gemmGrid) {
        gemm_body<unsigned short>(A, Wg, C, N, blockIdx.x);
        return;
    }
    int g = (blockIdx.x - gemmGrid) * 4 + (threadIdx.x >> 6);
    if (g >= G) return;
    pool_body(A, gstart, pbuf, poolLayer, g, threadIdx.x & 63);
}

// ---------------- CSR gather-aggregate + bias + ReLU (fp8, EIGHTH-wave) ------
// Chain-parallelism is the proven limiter (r8: 2 chains -14%, r9: 4 chains
// -8%). Continue: ONE NODE PER 8 LANES. fp8 row = 128B = 8 lanes x 16B
// (uint4, one dwordx4 per edge per lane). EIGHT independent chains per wave,
// 32 nodes/block, grid 3125. Each lane decodes 16 fp8 features (VALU per
// edge unchanged vs r9 -- same total decode work, VALU has headroom).
// Tail = ONE masked batch (idx clamped to e-1, weight zeroed; r3-proven).
__global__ __launch_bounds__(256) void k_aggregate(const unsigned char* __restrict__ t,
                                                   const int* __restrict__ indptr,
                                                   const int2* __restrict__ adj,
                                                   const float* __restrict__ bias,
                                                   unsigned short* __restrict__ h, int N) {
    int node = blockIdx.x * 32 + (threadIdx.x >> 3);   // 8-lane group index
    if (node >= N) return;
    int fl = threadIdx.x & 7;          // 16B chunk: features 16*fl .. 16*fl+15
    int s = indptr[node], e = indptr[node + 1];   // e > s (self-loop)
    const uint4* tu16 = (const uint4*)t;  // 16B = 16 fp8 features

    float a[16];
#pragma unroll
    for (int i = 0; i < 16; ++i) a[i] = 0.f;

    int p = s;
    for (; p + 7 < e; p += 8) {        // full batches: 8 edges per group
        uint4 v[8];
        float w[8];
#pragma unroll
        for (int u = 0; u < 8; ++u) {
            int2 ae = adj[p + u];      // uniform within the 8-lane group
            w[u] = __int_as_float(ae.y);
            v[u] = tu16[(size_t)ae.x * 8 + fl];
        }
#pragma unroll
        for (int u = 0; u < 8; ++u) {
            a[0]  = fmaf(w[u], fp8_dec<0>(v[u].x), a[0]);
            a[1]  = fmaf(w[u], fp8_dec<1>(v[u].x), a[1]);
            a[2]  = fmaf(w[u], fp8_dec<2>(v[u].x), a[2]);
            a[3]  = fmaf(w[u], fp8_dec<3>(v[u].x), a[3]);
            a[4]  = fmaf(w[u], fp8_dec<0>(v[u].y), a[4]);
            a[5]  = fmaf(w[u], fp8_dec<1>(v[u].y), a[5]);
            a[6]  = fmaf(w[u], fp8_dec<2>(v[u].y), a[6]);
            a[7]  = fmaf(w[u], fp8_dec<3>(v[u].y), a[7]);
            a[8]  = fmaf(w[u], fp8_dec<0>(v[u].z), a[8]);
            a[9]  = fmaf(w[u], fp8_dec<1>(v[u].z), a[9]);
            a[10] = fmaf(w[u], fp8_dec<2>(v[u].z), a[10]);
            a[11] = fmaf(w[u], fp8_dec<3>(v[u].z), a[11]);
            a[12] = fmaf(w[u], fp8_dec<0>(v[u].w), a[12]);
            a[13] = fmaf(w[u], fp8_dec<1>(v[u].w), a[13]);
            a[14] = fmaf(w[u], fp8_dec<2>(v[u].w), a[14]);
            a[15] = fmaf(w[u], fp8_dec<3>(v[u].w), a[15]);
        }
    }
    if (p < e) {                        // one masked batch covers the tail
        uint4 v[8];
        float w[8];
#pragma unroll
        for (int u = 0; u < 8; ++u) {
            int idx = p + u;
            int2 ae = adj[idx < e ? idx : e - 1];
            w[u] = (idx < e) ? __int_as_float(ae.y) : 0.f;
            v[u] = tu16[(size_t)ae.x * 8 + fl];
        }
#pragma unroll
        for (int u = 0; u < 8; ++u) {
            a[0]  = fmaf(w[u], fp8_dec<0>(v[u].x), a[0]);
            a[1]  = fmaf(w[u], fp8_dec<1>(v[u].x), a[1]);
            a[2]  = fmaf(w[u], fp8_dec<2>(v[u].x), a[2]);
            a[3]  = fmaf(w[u], fp8_dec<3>(v[u].x), a[3]);
            a[4]  = fmaf(w[u], fp8_dec<0>(v[u].y), a[4]);
            a[5]  = fmaf(w[u], fp8_dec<1>(v[u].y), a[5]);
            a[6]  = fmaf(w[u], fp8_dec<2>(v[u].y), a[6]);
            a[7]  = fmaf(w[u], fp8_dec<3>(v[u].y), a[7]);
            a[8]  = fmaf(w[u], fp8_dec<0>(v[u].z), a[8]);
            a[9]  = fmaf(w[u], fp8_dec<1>(v[u].z), a[9]);
            a[10] = fmaf(w[u], fp8_dec<2>(v[u].z), a[10]);
            a[11] = fmaf(w[u], fp8_dec<3>(v[u].z), a[11]);
            a[12] = fmaf(w[u], fp8_dec<0>(v[u].w), a[12]);
            a[13] = fmaf(w[u], fp8_dec<1>(v[u].w), a[13]);
            a[14] = fmaf(w[u], fp8_dec<2>(v[u].w), a[14]);
            a[15] = fmaf(w[u], fp8_dec<3>(v[u].w), a[15]);
        }
    }
    int fb = fl * 16;
    uint4 pk0, pk1;
    {
        float4 b0 = *(const float4*)(bias + fb);
        float4 b1 = *(const float4*)(bias + fb + 4);
        float4 b2 = *(const float4*)(bias + fb + 8);
        float4 b3 = *(const float4*)(bias + fb + 12);
        pk0.x = (unsigned int)f2bf(fmaxf(a[0]  + b0.x, 0.f)) |
                ((unsigned int)f2bf(fmaxf(a[1]  + b0.y, 0.f)) << 16);
        pk0.y = (unsigned int)f2bf(fmaxf(a[2]  + b0.z, 0.f)) |
                ((unsigned int)f2bf(fmaxf(a[3]  + b0.w, 0.f)) << 16);
        pk0.z = (unsigned int)f2bf(fmaxf(a[4]  + b1.x, 0.f)) |
                ((unsigned int)f2bf(fmaxf(a[5]  + b1.y, 0.f)) << 16);
        pk0.w = (unsigned int)f2bf(fmaxf(a[6]  + b1.z, 0.f)) |
                ((unsigned int)f2bf(fmaxf(a[7]  + b1.w, 0.f)) << 16);
        pk1.x = (unsigned int)f2bf(fmaxf(a[8]  + b2.x, 0.f)) |
                ((unsigned int)f2bf(fmaxf(a[9]  + b2.y, 0.f)) << 16);
        pk1.y = (unsigned int)f2bf(fmaxf(a[10] + b2.z, 0.f)) |
                ((unsigned int)f2bf(fmaxf(a[11] + b2.w, 0.f)) << 16);
        pk1.z = (unsigned int)f2bf(fmaxf(a[12] + b3.x, 0.f)) |
                ((unsigned int)f2bf(fmaxf(a[13] + b3.y, 0.f)) << 16);
        pk1.w = (unsigned int)f2bf(fmaxf(a[14] + b3.z, 0.f)) |
                ((unsigned int)f2bf(fmaxf(a[15] + b3.w, 0.f)) << 16);
    }
    uint4* hp = (uint4*)(h + (size_t)node * HID);
    hp[fl * 2]     = pk0;              // 8 lanes x 32B = 256B contiguous
    hp[fl * 2 + 1] = pk1;
}

// ---------------- standalone pool (used for the final layer) -----------------
__global__ __launch_bounds__(256) void k_pool(const unsigned short* __restrict__ h,
                                              const int* __restrict__ gstart,
                                              float* __restrict__ pbuf,
                                              int layer, int G) {
    int g = blockIdx.x * 4 + (threadIdx.x >> 6);
    if (g >= G) return;
    pool_body(h, gstart, pbuf, layer, g, threadIdx.x & 63);
}

// ---------------- MLP head: Z[G,640] = relu(P[G,640] @ Wl1 + bl1) ------------
__global__ __launch_bounds__(256) void k_head1(const float* __restrict__ P,
                                               const float* __restrict__ Wl1,
                                               const float* __restrict__ bl1,
                                               float* __restrict__ Z, int G) {
    __shared__ float As[64][68];
    __shared__ float Ws[64][64];
    const int tid = threadIdx.x;
    const int tr = tid >> 4;
    const int tc = tid & 15;
    const int gBase = blockIdx.x * 64;
    const int cBase = blockIdx.y * 64;

    float acc[4][4];
#pragma unroll
    for (int i = 0; i < 4; ++i)
#pragma unroll
        for (int j = 0; j < 4; ++j) acc[i][j] = 0.f;

    for (int kb = 0; kb < 640; kb += 64) {
#pragma unroll
        for (int i = 0; i < 4; ++i) {
            int f4 = tid + i * 256;
            int r  = f4 >> 4;
            int kc = (f4 & 15) << 2;
            int gg = gBase + r;
            float4 v = {0.f, 0.f, 0.f, 0.f};
            if (gg < G) v = *(const float4*)(P + (size_t)gg * 640 + kb + kc);
            As[kc + 0][r] = v.x; As[kc + 1][r] = v.y;
            As[kc + 2][r] = v.z; As[kc + 3][r] = v.w;
        }
#pragma unroll
        for (int i = 0; i < 4; ++i) {
            int f4 = tid + i * 256;
            int k  = f4 >> 4;
            int c4 = (f4 & 15) << 2;
            *(float4*)&Ws[k][c4] =
                *(const float4*)(Wl1 + (size_t)(kb + k) * 640 + cBase + c4);
        }
        __syncthreads();
#pragma unroll
        for (int k = 0; k < 64; ++k) {
            float a[4], w[4];
            *(float4*)&a[0] = *(const float4*)&As[k][tr * 4];
            *(float4*)&w[0] = *(const float4*)&Ws[k][tc * 4];
#pragma unroll
            for (int i = 0; i < 4; ++i)
#pragma unroll
                for (int j = 0; j < 4; ++j)
                    acc[i][j] = fmaf(a[i], w[j], acc[i][j]);
        }
        __syncthreads();
    }
#pragma unroll
    for (int i = 0; i < 4; ++i) {
        int gg = gBase + tr * 4 + i;
        if (gg < G) {
            float4 o;
            o.x = fmaxf(acc[i][0] + bl1[cBase + tc * 4 + 0], 0.f);
            o.y = fmaxf(acc[i][1] + bl1[cBase + tc * 4 + 1], 0.f);
            o.z = fmaxf(acc[i][2] + bl1[cBase + tc * 4 + 2], 0.f);
            o.w = fmaxf(acc[i][3] + bl1[cBase + tc * 4 + 3], 0.f);
            *(float4*)(Z + (size_t)gg * 640 + cBase + tc * 4) = o;
        }
    }
}

__global__ void k_fc2(const float* __restrict__ zbuf, const float* __restrict__ Wl2,
                      const float* __restrict__ bl2, float* __restrict__ out) {
    int g = blockIdx.x;
    int t = threadIdx.x;  // 128 threads = 2 waves
    float s = 0.f;
    for (int k = t; k < 640; k += 128) s = fmaf(zbuf[(size_t)g * 640 + k], Wl2[k], s);
#pragma unroll
    for (int off = 32; off > 0; off >>= 1) s += __shfl_down(s, off);
    __shared__ float ws[2];
    if ((t & 63) == 0) ws[t >> 6] = s;
    __syncthreads();
    if (t == 0) out[g] = ws[0] + ws[1] + bl2[0];
}

// ---------------- driver ----------------
extern "C" void kernel_launch(void* const* d_in, const int* in_sizes, int n_in,
                              void* d_out, int out_size, void* d_ws, size_t ws_size,
                              hipStream_t stream) {
    const float* x    = (const float*)d_in[0];
    const int*   edge = (const int*)d_in[1];
    const int*   bat  = (const int*)d_in[2];
    const float* W1   = (const float*)d_in[3];
    const float* b1   = (const float*)d_in[4];
    const float* W2   = (const float*)d_in[5];
    const float* b2   = (const float*)d_in[6];
    const float* W3   = (const float*)d_in[7];
    const float* b3   = (const float*)d_in[8];
    const float* W4   = (const float*)d_in[9];
    const float* b4   = (const float*)d_in[10];
    const float* Wl1  = (const float*)d_in[11];
    const float* bl1  = (const float*)d_in[12];
    const float* Wl2  = (const float*)d_in[13];
    const float* bl2  = (const float*)d_in[14];
    float*       out  = (float*)d_out;

    const int N = in_sizes[2];       // 100000
    const int E = in_sizes[1] / 2;   // 1600000
    const int G = out_size;          // 512
    (void)n_in; (void)ws_size;

    (void)hipGetLastError();  // clear any stale error

    // ---- workspace carve ----
    size_t off = 0;
    auto alloc = [&](size_t bytes) -> void* {
        void* p = (void*)((char*)d_ws + off);
        off += (bytes + 255) & ~(size_t)255;
        return p;
    };
    unsigned char*  buf0 = (unsigned char*)alloc((size_t)N * HID);       // t, fp8
    unsigned short* buf1 = (unsigned short*)alloc((size_t)N * HID * 2);  // h, bf16
    unsigned short* Wg   = (unsigned short*)alloc((size_t)4 * 16384 * 2); // swizzled W1..4
    float* dinv   = (float*)alloc((size_t)N * 4);
    int*   degI   = (int*)alloc((size_t)N * 4);
    int*   rank   = (int*)alloc((size_t)E * 4);
    int*   indptr = (int*)alloc((size_t)(N + 1) * 4);
    int*   partial= (int*)alloc((size_t)N * 4);
    int*   bsums  = (int*)alloc((size_t)1024 * 4);
    int2*  adj    = (int2*)alloc((size_t)(E + N) * 8);
    int*   gstart = (int*)alloc((size_t)(G + 1) * 4);
    float* pbuf   = (float*)alloc((size_t)G * 640 * 4);
    float* zbuf   = (float*)alloc((size_t)G * 640 * 4);

    const int* rowv = edge;      // sources
    const int* colv = edge + E;  // destinations

    // ---- K1: histogram(+rank) || layer-0 GEMM || wprep || gbounds ----
    hipMemsetAsync(degI, 0, (size_t)N * 4, stream);
    const int degGrid  = (E + 255) / 256;
    const int gemmGrid = (N + 127) / 128;
    const int gbGrid   = (G + 256) / 256;
    k_prep_gemm<<<degGrid + gemmGrid + 256 + gbGrid, 256, 0, stream>>>(
        colv, degI, rank, x, W1, buf0, W2, W3, W4, Wg, bat, gstart,
        E, N, G, degGrid, gemmGrid);

    // ---- scans ----
    const int scanBlocks = (N + 1023) / 1024;
    k_scan_part<<<scanBlocks, 1024, 0, stream>>>(degI, partial, bsums, N);
    k_scan_tops<<<1, 1024, 0, stream>>>(bsums, indptr, scanBlocks, N);
    k_scan_fix<<<(N + 255) / 256, 256, 0, stream>>>(partial, bsums, degI,
                                                    indptr, dinv, N);

    // ---- atomic-free scatter ----
    const int scatGrid = (E + N + 255) / 256;
    k_scat<<<scatGrid, 256, 0, stream>>>(rowv, colv, dinv, indptr, rank, adj, E, N);

    // ---- 5 GCN layers (layer 5 reuses W4/b4, matching the reference) ----
    const int aggGrid  = (N + 31) / 32;  // one node per 8 LANES, 32/block
    const int poolGrid = (G + 3) / 4;

    // layer 1
    k_aggregate<<<aggGrid, 256, 0, stream>>>(buf0, indptr, adj, b1, buf1, N);
    // layers 2..5: gemm (+ pool rider of previous h) then aggregate
    const float* bs_[4] = {b2, b3, b4, b4};
    const int Wi_[4] = {1, 2, 3, 3};
    for (int i = 0; i < 4; ++i) {
        k_gemm_pool<<<gemmGrid + poolGrid, 256, 0, stream>>>(
            buf1, Wg + Wi_[i] * 16384, buf0, N, gstart, pbuf, i, G, gemmGrid);
        k_aggregate<<<aggGrid, 256, 0, stream>>>(buf0, indptr, adj, bs_[i], buf1, N);
    }
    k_pool<<<poolGrid, 256, 0, stream>>>(buf1, gstart, pbuf, 4, G);

    // ---- MLP head ----
    dim3 hgrid((G + 63) / 64, 10);   // 640 output cols / 64
    k_head1<<<hgrid, 256, 0, stream>>>(pbuf, Wl1, bl1, zbuf, G);
    k_fc2<<<G, 128, 0, stream>>>(zbuf, Wl2, bl2, out);

    // sentinel: some launch failed synchronously (absmax ~= 48)
    if (hipGetLastError() != hipSuccess)
        hipMemsetAsync(d_out, 0x42, (size_t)out_size * 4, stream);
}